// Round 10
// baseline (27.220 us; speedup 1.0000x reference)
//
#include <hip/hip_runtime.h>

// RuleNet: out[b] = 5 + sum_c rw[c] * min_j( mu[c,j]*x[b,j] + (1-mu[c,j]) )
// with x = [x0, 1-x0], mu = sigmoid(conjunctions).
// Rewrite: fit(b,c) = 1 - max_v max( mu1[c,v]*(1-x0[b,v]), mu2[c,v]*x0[b,v] )
//          mu1*(1-x) = fma(-mu1, x, mu1).
//
// R10: software-pipelined mu stream (8 stages x 4 v, depth-2 prefetch) to
// remove the per-half vmcnt(0) lockstep stalls of R8. R8 geometry otherwise:
// 2 c/lane, BPB=8, LDS x broadcast, pinned-VGPR mu, fused atomic epilogue.

#define B_    1024
#define C_    512
#define V_    256
#define TWOV  512

#define CPW    128             // conjunctions per wave (two per lane)
#define NCHUNK (C_ / CPW)      // 4 c-chunks
#define BPB    8               // batches per block (== WAVES)
#define NBG    (B_ / BPB)      // 128 b-groups
#define WAVES  8               // waves per block, v-range split 8 x 32
#define VPW    32              // v per wave
#define NE     8               // pipeline stages per wave (4 v each)

// ---------- kernel 1: sigmoid + transpose, plus out[b]=5.0 init ----------
// float2 element (v>>1)*1024 + c*2 + (v&1) = (mu1[v], mu2[v])
//  => float4 muT4[vp][c] = (mu1[2vp], mu2[2vp], mu1[2vp+1], mu2[2vp+1])
__global__ __launch_bounds__(256) void k_prep(const float* __restrict__ conj,
                                              float2* __restrict__ muT2,
                                              float* __restrict__ out) {
    const int c = blockIdx.x;        // 512 blocks
    const int v = threadIdx.x;       // 256 threads, coalesced loads
    if (c < 4) out[c * 256 + v] = 5.0f;   // init accumulator target
    float z1 = conj[(size_t)c * TWOV + v];
    float z2 = conj[(size_t)c * TWOV + V_ + v];
    float m1 = 1.0f / (1.0f + __expf(-z1));
    float m2 = 1.0f / (1.0f + __expf(-z2));
    muT2[(size_t)(v >> 1) * (2 * C_) + c * 2 + (v & 1)] = make_float2(m1, m2);
}

// ---------- kernel 2: main fuzzy-AND + fused weighted-sum epilogue ----------
__global__ __launch_bounds__(512, 4) void k_main(const float* __restrict__ x0,
                                                 const float4* __restrict__ muT4,
                                                 const float* __restrict__ rw,
                                                 float* __restrict__ out) {
    const int tid   = threadIdx.x;
    const int lane  = tid & 63;
    const int wave  = tid >> 6;
    const int chunk = blockIdx.y;                // 4 chunks of 128 c
    const int cA    = chunk * CPW + lane;        // lane's first conjunction
    const int cB    = cA + 64;                   // lane's second conjunction
    const int bg    = blockIdx.x;                // 128 groups of 8 batches
    const int v0    = wave * VPW;                // this wave's v-range

    __shared__ float4 xs[BPB * V_ / 4];          // 8 KB: x rows of this b-group
    __shared__ float  red[2 * BPB * WAVES * 64]; // 32 KB: cross-wave max combine

    // x global load issued FIRST: the ds_write below then waits only on this
    // load (graded vmcnt), not on the mu stream issued after it.
    const float4* xg = reinterpret_cast<const float4*>(x0 + (size_t)bg * BPB * V_);
    float4 xv = xg[tid];

    const float4* mup = muT4 + (size_t)(v0 >> 1) * C_ + cA;

    // pipeline registers: stage q covers v = v0+4q .. v0+4q+3
    float4 A[NE][2], Bv[NE][2];
#define ISSUE(q) do { \
        A[q][0]  = mup[(size_t)(2*(q)    ) * C_]; \
        A[q][1]  = mup[(size_t)(2*(q) + 1) * C_]; \
        Bv[q][0] = mup[(size_t)(2*(q)    ) * C_ + 64]; \
        Bv[q][1] = mup[(size_t)(2*(q) + 1) * C_ + 64]; \
    } while (0)
#define PINq(q) do { \
        asm volatile("" : "+v"(A[q][0].x),  "+v"(A[q][0].y),  "+v"(A[q][0].z),  "+v"(A[q][0].w), \
                          "+v"(A[q][1].x),  "+v"(A[q][1].y),  "+v"(A[q][1].z),  "+v"(A[q][1].w)); \
        asm volatile("" : "+v"(Bv[q][0].x), "+v"(Bv[q][0].y), "+v"(Bv[q][0].z), "+v"(Bv[q][0].w), \
                          "+v"(Bv[q][1].x), "+v"(Bv[q][1].y), "+v"(Bv[q][1].z), "+v"(Bv[q][1].w)); \
    } while (0)

    // prologue: 2 stages in flight before the sync
    ISSUE(0);
    ISSUE(1);

    float mA[BPB], mB[BPB];
#pragma unroll
    for (int i = 0; i < BPB; ++i) { mA[i] = 0.0f; mB[i] = 0.0f; }

    xs[tid] = xv;          // waits only the x load (mu stays outstanding)
    __syncthreads();

    const int xbase = v0 >> 2;

#pragma unroll
    for (int q = 0; q < NE; ++q) {
        PINq(q);                               // graded vmcnt: only Eq's 4 loads
        if (q + 2 < NE) ISSUE(q + 2);          // keep pipeline depth 2
#pragma unroll
        for (int bi = 0; bi < BPB; ++bi) {
            // wave-uniform LDS read: 4 v for batch bi (broadcast, ~free)
            float4 xc = xs[bi * (V_ / 4) + xbase + q];
            float ma = mA[bi], mb = mB[bi];
            ma = fmaxf(ma, fmaxf(__builtin_fmaf(-A[q][0].x, xc.x, A[q][0].x),  A[q][0].y  * xc.x));
            ma = fmaxf(ma, fmaxf(__builtin_fmaf(-A[q][0].z, xc.y, A[q][0].z),  A[q][0].w  * xc.y));
            ma = fmaxf(ma, fmaxf(__builtin_fmaf(-A[q][1].x, xc.z, A[q][1].x),  A[q][1].y  * xc.z));
            ma = fmaxf(ma, fmaxf(__builtin_fmaf(-A[q][1].z, xc.w, A[q][1].z),  A[q][1].w  * xc.w));
            mb = fmaxf(mb, fmaxf(__builtin_fmaf(-Bv[q][0].x, xc.x, Bv[q][0].x), Bv[q][0].y * xc.x));
            mb = fmaxf(mb, fmaxf(__builtin_fmaf(-Bv[q][0].z, xc.y, Bv[q][0].z), Bv[q][0].w * xc.y));
            mb = fmaxf(mb, fmaxf(__builtin_fmaf(-Bv[q][1].x, xc.z, Bv[q][1].x), Bv[q][1].y * xc.z));
            mb = fmaxf(mb, fmaxf(__builtin_fmaf(-Bv[q][1].z, xc.w, Bv[q][1].z), Bv[q][1].w * xc.w));
            mA[bi] = ma; mB[bi] = mb;
        }
    }
#undef ISSUE
#undef PINq

    // cross-wave max combine: red[cc][bi][wave][lane] (tid-consecutive writes)
#pragma unroll
    for (int bi = 0; bi < BPB; ++bi) {
        red[bi * (WAVES * 64) + tid] = mA[bi];
        red[(BPB + bi) * (WAVES * 64) + tid] = mB[bi];
    }
    __syncthreads();

    // wave w finishes batch bi = w (all 8 waves in parallel)
    float ma = red[wave * (WAVES * 64) + lane];
    float mb = red[(BPB + wave) * (WAVES * 64) + lane];
#pragma unroll
    for (int k = 1; k < WAVES; ++k) {
        ma = fmaxf(ma, red[wave * (WAVES * 64) + k * 64 + lane]);
        mb = fmaxf(mb, red[(BPB + wave) * (WAVES * 64) + k * 64 + lane]);
    }
    float s = rw[cA] * (1.0f - ma) + rw[cB] * (1.0f - mb);
    // butterfly sum across 64 lanes = sum over this chunk's 128 conjunctions
    s += __shfl_xor(s, 1, 64);
    s += __shfl_xor(s, 2, 64);
    s += __shfl_xor(s, 4, 64);
    s += __shfl_xor(s, 8, 64);
    s += __shfl_xor(s, 16, 64);
    s += __shfl_xor(s, 32, 64);
    if (lane == 0)
        atomicAdd(&out[bg * BPB + wave], s);   // 4 adds per element (one per chunk)
}

// ---------- fallback (ws too small): naive but correct ----------
__global__ __launch_bounds__(256) void k_naive(const float* __restrict__ x0,
                                               const float* __restrict__ conj,
                                               const float* __restrict__ rw,
                                               float* __restrict__ out) {
    int b = blockIdx.x;
    int t = threadIdx.x;
    __shared__ float red[256];
    float acc = 0.0f;
    for (int c = t; c < C_; c += 256) {
        float m = 0.0f;
        for (int v = 0; v < V_; ++v) {
            float mu1 = 1.0f / (1.0f + expf(-conj[(size_t)c * TWOV + v]));
            float mu2 = 1.0f / (1.0f + expf(-conj[(size_t)c * TWOV + V_ + v]));
            float x = x0[(size_t)b * V_ + v];
            m = fmaxf(m, fmaxf(mu1 * (1.0f - x), mu2 * x));
        }
        acc += rw[c] * (1.0f - m);
    }
    red[t] = acc;
    __syncthreads();
    for (int s = 128; s > 0; s >>= 1) {
        if (t < s) red[t] += red[t + s];
        __syncthreads();
    }
    if (t == 0) out[b] = 5.0f + red[0];
}

extern "C" void kernel_launch(void* const* d_in, const int* in_sizes, int n_in,
                              void* d_out, int out_size, void* d_ws, size_t ws_size,
                              hipStream_t stream) {
    const float* x0   = (const float*)d_in[0];
    const float* conj = (const float*)d_in[1];
    const float* rw   = (const float*)d_in[2];
    float* out = (float*)d_out;

    const size_t mu_floats = (size_t)(V_ / 2) * C_ * 4;   // 262144 floats (1 MB)
    const size_t need = mu_floats * sizeof(float);

    if (ws_size < need) {
        k_naive<<<B_, 256, 0, stream>>>(x0, conj, rw, out);
        return;
    }

    float4* muT4 = (float4*)d_ws;

    k_prep<<<C_, 256, 0, stream>>>(conj, (float2*)muT4, out);
    dim3 grid(NBG, NCHUNK);   // 128 x 4 = 512 blocks = exactly 2/CU;
                              // x-major = batch so concurrent blocks share mu in L2
    k_main<<<grid, 512, 0, stream>>>(x0, muT4, rw, out);
}